// Round 1
// 296.801 us; speedup vs baseline: 1.0301x; 1.0301x over previous
//
#include <hip/hip_runtime.h>

#define T_SEQ 2048
#define NHEAD 16
#define HS 64

typedef __bf16 bf16x8 __attribute__((ext_vector_type(8)));
typedef float f32x4 __attribute__((ext_vector_type(4)));

__device__ __forceinline__ unsigned short f2bf(float f) {
  union { float f; unsigned int u; } v; v.f = f;
  return (unsigned short)((v.u + 0x7fffu + ((v.u >> 16) & 1u)) >> 16);
}
__device__ __forceinline__ float bf2f(unsigned short h) {
  union { unsigned int u; float f; } v; v.u = ((unsigned int)h) << 16;
  return v.f;
}
__device__ __forceinline__ bf16x8 ld_bf8(const unsigned short* p) {
  return *(const bf16x8*)p;
}
__device__ __forceinline__ void st_bf8(unsigned short* p, bf16x8 v) {
  *(bf16x8*)p = v;
}
__device__ __forceinline__ bf16x8 cvt8(float4 a, float4 b) {
  bf16x8 r;
  r[0] = (__bf16)a.x; r[1] = (__bf16)a.y; r[2] = (__bf16)a.z; r[3] = (__bf16)a.w;
  r[4] = (__bf16)b.x; r[5] = (__bf16)b.y; r[6] = (__bf16)b.z; r[7] = (__bf16)b.w;
  return r;
}
// async global->LDS, 16B per lane; lds base must be wave-uniform (dest = base + lane*16)
__device__ __forceinline__ void gload_lds16(const void* g, void* l) {
  __builtin_amdgcn_global_load_lds(
      (const __attribute__((address_space(1))) unsigned int*)g,
      (__attribute__((address_space(3))) unsigned int*)l, 16, 0, 0);
}

// f32 -> bf16 (RNE, same rounding as previous inline staging), 8 elems/thread
__global__ __launch_bounds__(256) void cvt_bf16(const float* __restrict__ src,
                                                unsigned short* __restrict__ dst) {
  const size_t i = ((size_t)blockIdx.x * 256 + threadIdx.x) * 8;
  const float4 a = *(const float4*)(src + i);
  const float4 b = *(const float4*)(src + i + 4);
  st_bf8(dst + i, cvt8(a, b));
}

// C[m,n] = sum_k A[m,k]*B[n,k];  A bf16 [M][K]; B bf16 [N][K] (or f32 if bf32).
// m97 structure: 128x128 tile, BK=64, 4 waves, global_load_lds width-16 staging.
// mode 0: C row-major [M,N] f32.  mode 1: qkv scatter (N=3072) bf16.
__global__ __launch_bounds__(256, 2) void gemm_bt(
    const unsigned short* __restrict__ A, const void* __restrict__ Bv,
    float* __restrict__ Cout,
    unsigned short* __restrict__ qb, unsigned short* __restrict__ kb,
    unsigned short* __restrict__ vtb,
    int M, int N, int K, int bf32, int mode) {
  __shared__ unsigned short As[128 * 64];
  __shared__ unsigned short Bs[128 * 64];
  const int tid = threadIdx.x;
  const int wid = tid >> 6, lane = tid & 63;
  const int quad = lane >> 4, l16 = lane & 15;
  const int m0 = blockIdx.y * 128, n0 = blockIdx.x * 128;
  const int wm = (wid >> 1) * 64, wn = (wid & 1) * 64;
  // gload staging coords: wave wid, shot j covers rows wid*32+j*8+(lane>>3), col (lane&7)*8
  const int srow = lane >> 3;
  const int scol = (lane & 7) * 8;
  // f32-B fallback staging coords (all 256 threads)
  const int brow = tid >> 3;
  const int bcol = (tid & 7) * 8;
  const unsigned short* Bh = (const unsigned short*)Bv;
  const float* Bf = (const float*)Bv;
  f32x4 acc[4][4] = {};
  const int nkt = K >> 6;
  for (int kt = 0; kt < nkt; ++kt) {
    const int k0 = kt * 64;
    // A: global -> LDS direct (linear dest = wave base + lane*16B)
    #pragma unroll
    for (int j = 0; j < 4; ++j) {
      const int rr = wid * 32 + j * 8 + srow;
      gload_lds16(A + (size_t)(m0 + rr) * K + k0 + scol,
                  &As[(wid * 32 + j * 8) * 64]);
    }
    if (bf32) {
      bf16x8 bs8[4];
      #pragma unroll
      for (int j = 0; j < 4; ++j) {
        const float* p = Bf + (size_t)(n0 + j * 32 + brow) * K + k0 + bcol;
        bs8[j] = cvt8(*(const float4*)p, *(const float4*)(p + 4));
      }
      #pragma unroll
      for (int j = 0; j < 4; ++j)
        st_bf8(&Bs[(j * 32 + brow) * 64 + bcol], bs8[j]);   // prev-iter barrier protects
    } else {
      #pragma unroll
      for (int j = 0; j < 4; ++j) {
        const int rr = wid * 32 + j * 8 + srow;
        gload_lds16(Bh + (size_t)(n0 + rr) * K + k0 + scol,
                    &Bs[(wid * 32 + j * 8) * 64]);
      }
    }
    __syncthreads();   // compiler drains vmcnt/lgkmcnt before barrier
    #pragma unroll
    for (int ks = 0; ks < 2; ++ks) {
      bf16x8 af[4], bfr[4];
      #pragma unroll
      for (int mt = 0; mt < 4; ++mt)
        af[mt] = ld_bf8(&As[(wm + mt * 16 + l16) * 64 + ks * 32 + quad * 8]);
      #pragma unroll
      for (int nt = 0; nt < 4; ++nt)
        bfr[nt] = ld_bf8(&Bs[(wn + nt * 16 + l16) * 64 + ks * 32 + quad * 8]);
      #pragma unroll
      for (int mt = 0; mt < 4; ++mt)
        #pragma unroll
        for (int nt = 0; nt < 4; ++nt)
          acc[mt][nt] = __builtin_amdgcn_mfma_f32_16x16x32_bf16(af[mt], bfr[nt], acc[mt][nt], 0, 0, 0);
    }
    __syncthreads();   // all reads done before next iter's gloads overwrite LDS
  }
  #pragma unroll
  for (int mt = 0; mt < 4; ++mt) {
    #pragma unroll
    for (int nt = 0; nt < 4; ++nt) {
      const int n = n0 + wn + nt * 16 + l16;
      #pragma unroll
      for (int r = 0; r < 4; ++r) {
        const int m = m0 + wm + mt * 16 + quad * 4 + r;
        if (mode == 0) {
          Cout[(size_t)m * N + n] = acc[mt][nt][r];   // fp32 output
        } else {
          const unsigned short val = f2bf(acc[mt][nt][r]);
          const int b = m >> 11, t = m & (T_SEQ - 1);
          const int which = n >> 10, c = n & 1023;
          const int h = c >> 6, d = c & 63;
          const int bh = b * NHEAD + h;
          if (which == 0)      qb[((size_t)bh * T_SEQ + t) * HS + d] = val;
          else if (which == 1) kb[((size_t)bh * T_SEQ + t) * HS + d] = val;
          else                 vtb[((size_t)bh * HS + d) * T_SEQ + t] = val;  // V transposed
        }
      }
    }
  }
}

// Reference's rolled-RoPE:
//   er[i] = x[2i]*c[i] - x[(2i-1) mod 64]*s[i]
//   ep[i] = x[2i+1]*c[i] + er[(i+1) mod 32]*s[i]
__global__ __launch_bounds__(256, 1) void rope(unsigned short* __restrict__ qb,
                                               unsigned short* __restrict__ kb) {
  const int idx = blockIdx.x * 256 + threadIdx.x;
  unsigned short* buf = (idx < 65536 ? qb : kb) + (size_t)(idx & 65535) * HS;
  const int t = idx & (T_SEQ - 1);
  float x[64];
  #pragma unroll
  for (int j = 0; j < 64; ++j) x[j] = bf2f(buf[j]);
  __asm__ volatile("" ::: "memory");
  float c[32], s[32], er[32];
  #pragma unroll
  for (int i = 0; i < 32; ++i) {
    const float ang = (float)t * exp2f(-0.41524101186092029f * (float)i);
    c[i] = cosf(ang); s[i] = sinf(ang);
  }
  #pragma unroll
  for (int i = 0; i < 32; ++i)
    er[i] = x[2 * i] * c[i] - x[(2 * i + 63) & 63] * s[i];
  #pragma unroll
  for (int i = 0; i < 32; ++i) {
    const float ep = x[2 * i + 1] * c[i] + er[(i + 1) & 31] * s[i];
    buf[2 * i]     = f2bf(er[i]);
    buf[2 * i + 1] = f2bf(ep);
  }
}

// Flash attention v2: 4 INDEPENDENT waves per 256-thr block (no barriers between
// them) so up to 32 waves/CU can be resident (64-thr blocks cap at ~16 wg/CU).
// 4096 units sorted longest-first; unit = blockIdx.x*4 + wid.
// 64-wide K passes: 8 QK MFMA + 8 PV MFMA per pass; V loads issued before softmax.
// P via per-wave LDS tile, padded stride 72; s_setprio(1) around MFMA clusters (T5).
__global__ __launch_bounds__(256) void attn(
    const unsigned short* __restrict__ qb, const unsigned short* __restrict__ kb,
    const unsigned short* __restrict__ vt, unsigned short* __restrict__ yb) {
  __shared__ __bf16 Pl[4][16][72];
  const int wid = threadIdx.x >> 6;
  const int u = blockIdx.x * 4 + wid;  // 0..4095
  const int qi = 127 - (u >> 5);       // q-tile 0..127, longest first
  const int bh = u & 31;
  const int q0 = qi * 16;
  const int lane = threadIdx.x & 63;
  const int quad = lane >> 4, l16 = lane & 15;

  const unsigned short* qptr = qb + ((size_t)bh * T_SEQ + q0 + l16) * HS;
  const bf16x8 aq0 = ld_bf8(qptr + quad * 8);        // A-frag kk 0..31
  const bf16x8 aq1 = ld_bf8(qptr + 32 + quad * 8);   // A-frag kk 32..63
  f32x4 O[4] = {};
  float m_i[4], l_i[4], alpha[4];
  #pragma unroll
  for (int r = 0; r < 4; ++r) { m_i[r] = -1e30f; l_i[r] = 0.f; }

  const unsigned short* kbase = kb + (size_t)bh * T_SEQ * HS;
  const unsigned short* vbase = vt + (size_t)bh * HS * T_SEQ;
  const int kend = q0 + 15;

  for (int k0 = 0; k0 <= kend; k0 += 64) {
    // K B-frags: 4 S-tiles x 2 kk-chunks
    bf16x8 bk[4][2];
    #pragma unroll
    for (int t = 0; t < 4; ++t) {
      const unsigned short* kp = kbase + (size_t)(k0 + t * 16 + l16) * HS;
      bk[t][0] = ld_bf8(kp + quad * 8);
      bk[t][1] = ld_bf8(kp + 32 + quad * 8);
    }
    f32x4 S[4] = {};
    __builtin_amdgcn_s_setprio(1);
    #pragma unroll
    for (int t = 0; t < 4; ++t) {
      S[t] = __builtin_amdgcn_mfma_f32_16x16x32_bf16(aq0, bk[t][0], S[t], 0, 0, 0);
      S[t] = __builtin_amdgcn_mfma_f32_16x16x32_bf16(aq1, bk[t][1], S[t], 0, 0, 0);
    }
    __builtin_amdgcn_s_setprio(0);
    // V B-frags for both kk-chunks: issue now, consumed after softmax.
    bf16x8 vb[2][4];
    #pragma unroll
    for (int c = 0; c < 2; ++c)
      #pragma unroll
      for (int vg = 0; vg < 4; ++vg)
        vb[c][vg] = ld_bf8(vbase + (size_t)(vg * 16 + l16) * T_SEQ + k0 + c * 32 + quad * 8);
    // online softmax over 64 k-cols, 4 q-rows per lane (quad*4+r)
    #pragma unroll
    for (int r = 0; r < 4; ++r) {
      const int row = q0 + quad * 4 + r;
      float s[4];
      #pragma unroll
      for (int t = 0; t < 4; ++t)
        s[t] = (k0 + t * 16 + l16 <= row) ? S[t][r] * 0.125f : -1e30f;
      float tm = fmaxf(fmaxf(s[0], s[1]), fmaxf(s[2], s[3]));
      #pragma unroll
      for (int off = 1; off < 16; off <<= 1) tm = fmaxf(tm, __shfl_xor(tm, off, 64));
      const float mnew = fmaxf(m_i[r], tm);
      alpha[r] = __expf(m_i[r] - mnew);
      unsigned short h[4];
      float rs = 0.f;
      #pragma unroll
      for (int t = 0; t < 4; ++t) {
        h[t] = f2bf(__expf(s[t] - mnew));
        rs += bf2f(h[t]);                 // rounded-P denominator (matches numerator)
      }
      #pragma unroll
      for (int off = 1; off < 16; off <<= 1) rs += __shfl_xor(rs, off, 64);
      l_i[r] = l_i[r] * alpha[r] + rs;
      m_i[r] = mnew;
      #pragma unroll
      for (int t = 0; t < 4; ++t)
        Pl[wid][quad * 4 + r][t * 16 + l16] = __builtin_bit_cast(__bf16, h[t]);
    }
    #pragma unroll
    for (int vg = 0; vg < 4; ++vg)
      #pragma unroll
      for (int r = 0; r < 4; ++r) O[vg][r] *= alpha[r];
    // P A-frags from LDS (same-wave dependency -> compiler lgkmcnt)
    __builtin_amdgcn_s_setprio(1);
    #pragma unroll
    for (int c = 0; c < 2; ++c) {
      const bf16x8 pa = *(const bf16x8*)&Pl[wid][l16][c * 32 + quad * 8];
      #pragma unroll
      for (int vg = 0; vg < 4; ++vg)
        O[vg] = __builtin_amdgcn_mfma_f32_16x16x32_bf16(pa, vb[c][vg], O[vg], 0, 0, 0);
    }
    __builtin_amdgcn_s_setprio(0);
  }
  const int b = bh >> 4, h = bh & 15;
  #pragma unroll
  for (int r = 0; r < 4; ++r) {
    const float inv = 1.0f / fmaxf(l_i[r], 1e-30f);
    const int row = q0 + quad * 4 + r;
    #pragma unroll
    for (int vg = 0; vg < 4; ++vg)
      yb[((size_t)b * T_SEQ + row) * 1024 + h * HS + vg * 16 + l16] = f2bf(O[vg][r] * inv);
  }
}

extern "C" void kernel_launch(void* const* d_in, const int* in_sizes, int n_in,
                              void* d_out, int out_size, void* d_ws, size_t ws_size,
                              hipStream_t stream) {
  const float* x      = (const float*)d_in[0];   // FP32 inputs per reference
  const float* w_attn = (const float*)d_in[1];
  const float* w_proj = (const float*)d_in[2];
  float* out = (float*)d_out;                    // FP32 output per reference
  unsigned short* qb = (unsigned short*)d_ws;          // [32][2048][64] bf16, 8 MB
  unsigned short* kb = qb + (size_t)4194304;           // 8 MB
  unsigned short* vt = kb + (size_t)4194304;           // [32][64][2048] transposed, 8 MB
  unsigned short* yb = vt + (size_t)4194304;           // [2][2048][1024] bf16, 8 MB
  unsigned short* xb = yb;                             // alias: xb consumed (gemm1) before yb written (attn)
  unsigned short* wab = yb + (size_t)4194304;          // 6 MB (only if ws allows)
  unsigned short* wpb = wab + (size_t)3145728;         // 2 MB
  const int big = ws_size >= (size_t)40 * 1024 * 1024;

  // 0) pre-convert operands to bf16 (memory-bound, ~8 us total)
  cvt_bf16<<<dim3(2048), 256, 0, stream>>>(x, xb);
  if (big) {
    cvt_bf16<<<dim3(1536), 256, 0, stream>>>(w_attn, wab);
    cvt_bf16<<<dim3(512), 256, 0, stream>>>(w_proj, wpb);
  }
  // 1) qkv = x @ w_attn^T -> q/k/v layouts (global_load_lds fast path if big)
  if (big)
    gemm_bt<<<dim3(24, 32), 256, 0, stream>>>(xb, wab, nullptr, qb, kb, vt,
                                              4096, 3072, 1024, 0, 1);
  else
    gemm_bt<<<dim3(24, 32), 256, 0, stream>>>(xb, w_attn, nullptr, qb, kb, vt,
                                              4096, 3072, 1024, 1, 1);
  // 2) RoPE in-place on q, k
  rope<<<dim3(512), 256, 0, stream>>>(qb, kb);
  // 3) causal flash attention -> y bf16 (4 independent waves per block)
  attn<<<dim3(1024), 256, 0, stream>>>(qb, kb, vt, yb);
  // 4) out = y(bf16) @ w_proj^T -> FLOAT32
  if (big)
    gemm_bt<<<dim3(8, 32), 256, 0, stream>>>(yb, wpb, out, nullptr, nullptr, nullptr,
                                             4096, 1024, 1024, 0, 0);
  else
    gemm_bt<<<dim3(8, 32), 256, 0, stream>>>(yb, w_proj, out, nullptr, nullptr, nullptr,
                                             4096, 1024, 1024, 1, 0);
}